// Round 8
// baseline (380.268 us; speedup 1.0000x reference)
//
#include <hip/hip_runtime.h>

#define N_NODES 50000
#define N_EDGES 800000
#define D 128
#define PLANE ((size_t)N_NODES * D)
#define NCHUNK ((N_NODES + 255) / 256)  // 196

typedef float f32x4 __attribute__((ext_vector_type(4)));
typedef float f32x2 __attribute__((ext_vector_type(2)));
typedef short bf16x8 __attribute__((ext_vector_type(8)));

__device__ __forceinline__ unsigned short f2bf(float x) {
  unsigned int u = __float_as_uint(x);
  u += 0x7FFFu + ((u >> 16) & 1u);  // RNE
  return (unsigned short)(u >> 16);
}
__device__ __forceinline__ float bf2f(unsigned short h) {
  return __uint_as_float((unsigned int)h << 16);
}
// HW OCP e4m3 converts (gfx950)
__device__ __forceinline__ unsigned char f32_to_fp8(float x) {
  int p = __builtin_amdgcn_cvt_pk_fp8_f32(x, x, 0, false);
  return (unsigned char)(p & 0xFF);
}
__device__ __forceinline__ void fp8x4_to_f32(int pk, float* f) {
  f32x2 lo = __builtin_amdgcn_cvt_pk_f32_fp8(pk, false);
  f32x2 hi = __builtin_amdgcn_cvt_pk_f32_fp8(pk, true);
  f[0] = lo.x; f[1] = lo.y; f[2] = hi.x; f[3] = hi.y;
}

// ---------------- CSR build ----------------

__global__ __launch_bounds__(256) void count_deg(const int* __restrict__ dst,
                                                 int* __restrict__ cnt) {
  int e = blockIdx.x * blockDim.x + threadIdx.x;
  if (e < N_EDGES) atomicAdd(&cnt[dst[e]], 1);
}

__global__ __launch_bounds__(256) void scan_local(const int* __restrict__ cnt,
                                                  int* __restrict__ local,
                                                  int* __restrict__ partial) {
  __shared__ int s[256];
  int t = threadIdx.x;
  int i = blockIdx.x * 256 + t;
  int v = (i < N_NODES) ? cnt[i] : 0;
  s[t] = v;
  __syncthreads();
  for (int off = 1; off < 256; off <<= 1) {
    int tmp = (t >= off) ? s[t - off] : 0;
    __syncthreads();
    s[t] += tmp;
    __syncthreads();
  }
  if (i < N_NODES) local[i] = s[t] - v;
  if (t == 255) partial[blockIdx.x] = s[255];
}

__global__ __launch_bounds__(256) void scan_chunks(const int* __restrict__ partial,
                                                   int* __restrict__ chunk_off,
                                                   int* __restrict__ rowptr) {
  __shared__ int s[256];
  int t = threadIdx.x;
  int v = (t < NCHUNK) ? partial[t] : 0;
  s[t] = v;
  __syncthreads();
  for (int off = 1; off < 256; off <<= 1) {
    int tmp = (t >= off) ? s[t - off] : 0;
    __syncthreads();
    s[t] += tmp;
    __syncthreads();
  }
  if (t < NCHUNK) chunk_off[t] = s[t] - v;
  if (t == 255) rowptr[N_NODES] = s[255];
}

__global__ __launch_bounds__(256) void finalize_rows(const int* __restrict__ cnt,
                                                     const int* __restrict__ local,
                                                     const int* __restrict__ chunk_off,
                                                     int* __restrict__ rowptr,
                                                     int* __restrict__ cursor,
                                                     float* __restrict__ norm) {
  int i = blockIdx.x * 256 + threadIdx.x;
  if (i < N_NODES) {
    int r = local[i] + chunk_off[blockIdx.x];
    rowptr[i] = r;
    cursor[i] = r;
    int d = cnt[i];
    if (d < 1) d = 1;
    norm[i] = rsqrtf((float)d);
  }
}

__global__ __launch_bounds__(256) void fill_csr(const int* __restrict__ src,
                                                const int* __restrict__ dst,
                                                int* __restrict__ cursor,
                                                int* __restrict__ col) {
  int e = blockIdx.x * blockDim.x + threadIdx.x;
  if (e < N_EDGES) {
    int pos = atomicAdd(&cursor[dst[e]], 1);
    col[pos] = src[e];
  }
}

// ---------------- prep (after CSR): feats->bf16, feats*norm->fp8, weight transposes ----

#define CONV_THREADS ((int)(PLANE / 4))            // 1,600,000
#define WT_THREADS (2 * 3 * 128 * 256)             // 196,608
#define PREP_TOTAL (CONV_THREADS + WT_THREADS)

__global__ __launch_bounds__(256) void prep_all(const float* __restrict__ feats,
                                                const float* __restrict__ w0,
                                                const float* __restrict__ w,
                                                const float* __restrict__ v,
                                                const float* __restrict__ norm,
                                                unsigned short* __restrict__ feats_bf,
                                                unsigned char* __restrict__ feats_fp8,
                                                unsigned short* __restrict__ bt_h1,
                                                unsigned short* __restrict__ bt_out) {
  int idx = blockIdx.x * 256 + threadIdx.x;
  if (idx < CONV_THREADS) {
    float4 x = ((const float4*)feats)[idx];
    ushort4 o;
    o.x = f2bf(x.x);
    o.y = f2bf(x.y);
    o.z = f2bf(x.z);
    o.w = f2bf(x.w);
    ((ushort4*)feats_bf)[idx] = o;
    float nd = norm[idx >> 5];  // 32 float4s per 128-feat row
    int p = __builtin_amdgcn_cvt_pk_fp8_f32(x.x * nd, x.y * nd, 0, false);
    p = __builtin_amdgcn_cvt_pk_fp8_f32(x.z * nd, x.w * nd, p, true);
    ((int*)feats_fp8)[idx] = p;
    return;
  }
  idx -= CONV_THREADS;
  if (idx >= WT_THREADS) return;
  int buf = idx / 98304;
  int rem = idx - buf * 98304;
  int stack = rem / 32768;
  int rem2 = rem & 32767;
  int n = rem2 >> 8;
  int k = rem2 & 255;
  const float* srcm;
  int kk;
  if (k < 128) {
    srcm = (buf == 0) ? w0 : w;
    kk = k;
  } else {
    srcm = v;
    kk = k - 128;
  }
  float val = srcm[(size_t)stack * 16384 + (size_t)kk * 128 + n];
  unsigned short* dstb = (buf == 0) ? bt_h1 : bt_out;
  dstb[(size_t)stack * 32768 + (size_t)n * 256 + k] = f2bf(val);
}

// ---------------- persistent pull-mode SpMM over prescaled fp8 ----------------
// h layout: [node][NK*128] fp8 (NK=3 -> the 3 stacks interleaved per node, one
// contiguous 384 B region per edge). Values prescaled by norm[src], so the
// per-edge chain is col -> h only. Wave = one row at a time, grid-stride over
// rows (8192 persistent waves; refill cost amortized, degree raggedness
// averaged). lane: sub=lane>>3 (edge slot 0..7), c8=lane&7 (16-feat chunk).
// Butterfly xor 8/16/32 combines the 8 edge slots. Output bf16 plane-major.

template <int NK>
__global__ __launch_bounds__(256) void spmm_fp8(const unsigned char* __restrict__ h,
                                                const float* __restrict__ norm,
                                                const int* __restrict__ rowptr,
                                                const int* __restrict__ col,
                                                unsigned short* __restrict__ out) {
  int wave = blockIdx.x * 4 + (threadIdx.x >> 6);
  int nwaves = gridDim.x * 4;
  int lane = threadIdx.x & 63;
  int sub = lane >> 3;
  int c8 = lane & 7;

  for (int row = wave; row < N_NODES; row += nwaves) {
    int beg = rowptr[row], end = rowptr[row + 1];

    float acc[NK][16];
#pragma unroll
    for (int m = 0; m < NK; ++m)
#pragma unroll
      for (int j = 0; j < 16; ++j) acc[m][j] = 0.f;

#pragma unroll 2
    for (int e = beg; e < end; e += 8) {
      int eidx = e + sub;
      bool valid = eidx < end;
      int s = valid ? col[eidx] : 0;
      float msk = valid ? 1.f : 0.f;
      const unsigned char* hp = h + (size_t)s * (NK * 128) + c8 * 16;
#pragma unroll
      for (int m = 0; m < NK; ++m) {
        int4 pkt = *(const int4*)(hp + m * 128);
        float f[16];
        fp8x4_to_f32(pkt.x, f + 0);
        fp8x4_to_f32(pkt.y, f + 4);
        fp8x4_to_f32(pkt.z, f + 8);
        fp8x4_to_f32(pkt.w, f + 12);
#pragma unroll
        for (int j = 0; j < 16; ++j) acc[m][j] = fmaf(msk, f[j], acc[m][j]);
      }
    }

#pragma unroll
    for (int m = 0; m < NK; ++m)
#pragma unroll
      for (int j = 0; j < 16; ++j) {
        float vv = acc[m][j];
        vv += __shfl_xor(vv, 8);
        vv += __shfl_xor(vv, 16);
        vv += __shfl_xor(vv, 32);
        acc[m][j] = vv;
      }

    if (sub == 0) {
      float nd = norm[row];
#pragma unroll
      for (int m = 0; m < NK; ++m) {
        bf16x8 o0, o1;
#pragma unroll
        for (int j = 0; j < 8; ++j) {
          o0[j] = (short)f2bf(acc[m][j] * nd);
          o1[j] = (short)f2bf(acc[m][j + 8] * nd);
        }
        unsigned short* op = out + m * PLANE + (size_t)row * D + c8 * 16;
        *(bf16x8*)op = o0;
        *(bf16x8*)(op + 8) = o1;
      }
    }
  }
}

// ---------------- MFMA GEMM ----------------
// Block: 256 threads = 4 waves, M-tile 128 rows, N-tile 64 cols (blockIdx.y).
// B half-tile (64n x 256k bf16 = 32 KB) in LDS, XOR-swizzled (2-way max).
// Stacks looped in-kernel; shared-A fragments hoisted into registers.
// Fragments (m89/m120-verified): A[m=lane&15][k=(lane>>4)*8+j];
// B-frag = Bt[n=lane&15][k..]; C/D col=lane&15, row=(lane>>4)*4+reg.

__device__ __forceinline__ void stage_B64(unsigned short (*Bs)[256],
                                          const unsigned short* __restrict__ Btg,
                                          int nh, int tid) {
#pragma unroll
  for (int i = 0; i < 8; ++i) {
    int t = tid + i * 256;       // 0..2047 16B-chunks
    int n = t >> 5;              // 0..63
    int kc = t & 31;
    int kcs = kc ^ (n & 31);     // swizzle
    *(bf16x8*)&Bs[n][kcs * 8] = *(const bf16x8*)(Btg + (size_t)(nh + n) * 256 + kc * 8);
  }
}

__device__ __forceinline__ bf16x8 read_B64(const unsigned short (*Bs)[256], int n,
                                           int chunk) {
  return *(const bf16x8*)&Bs[n][(chunk ^ (n & 31)) * 8];
}

// layer-1: h1_fp8[node][stk][128] = fp8( relu(P @ w0[stk] + feats @ v[stk] + b) * norm[node] )
// P and feats shared across stacks -> A-frags loaded ONCE.
__global__ __launch_bounds__(256) void gemm_h1_fused(
    const unsigned short* __restrict__ P,
    const unsigned short* __restrict__ feats_bf,
    const unsigned short* __restrict__ Bt,
    const float* __restrict__ b0, const float* __restrict__ bv,
    const float* __restrict__ norm,
    unsigned char* __restrict__ h1_fp8) {
  __shared__ unsigned short Bs[64][256];
  int nh = blockIdx.y * 64;

  int tid = threadIdx.x;
  int lane = tid & 63;
  int wv = tid >> 6;
  int ln15 = lane & 15;
  int g = lane >> 4;

  int m0 = blockIdx.x * 128 + wv * 32;
  int r0 = m0 + ln15;
  int r1 = m0 + 16 + ln15;
  if (r0 >= N_NODES) r0 = N_NODES - 1;
  if (r1 >= N_NODES) r1 = N_NODES - 1;

  bf16x8 a0[8], a1[8];  // s=0..3 from P (k<128), s=4..7 from feats (k>=128)
#pragma unroll
  for (int s = 0; s < 4; ++s) {
    a0[s] = *(const bf16x8*)(P + (size_t)r0 * 128 + g * 8 + s * 32);
    a1[s] = *(const bf16x8*)(P + (size_t)r1 * 128 + g * 8 + s * 32);
    a0[s + 4] = *(const bf16x8*)(feats_bf + (size_t)r0 * 128 + g * 8 + s * 32);
    a1[s + 4] = *(const bf16x8*)(feats_bf + (size_t)r1 * 128 + g * 8 + s * 32);
  }

  for (int stk = 0; stk < 3; ++stk) {
    if (stk) __syncthreads();
    stage_B64(Bs, Bt + (size_t)stk * 32768, nh, tid);
    __syncthreads();

    f32x4 acc0[4], acc1[4];
#pragma unroll
    for (int nt = 0; nt < 4; ++nt) { acc0[nt] = (f32x4)(0.f); acc1[nt] = (f32x4)(0.f); }

#pragma unroll
    for (int s = 0; s < 8; ++s) {
#pragma unroll
      for (int nt = 0; nt < 4; ++nt) {
        bf16x8 bfr = read_B64(Bs, nt * 16 + ln15, s * 4 + g);
        acc0[nt] = __builtin_amdgcn_mfma_f32_16x16x32_bf16(a0[s], bfr, acc0[nt], 0, 0, 0);
        acc1[nt] = __builtin_amdgcn_mfma_f32_16x16x32_bf16(a1[s], bfr, acc1[nt], 0, 0, 0);
      }
    }

#pragma unroll
    for (int nt = 0; nt < 4; ++nt) {
      int colj = nh + nt * 16 + ln15;
      float bsum = b0[stk * 128 + colj] + bv[stk * 128 + colj];
#pragma unroll
      for (int r = 0; r < 4; ++r) {
        int mA = m0 + g * 4 + r;
        int mB = m0 + 16 + g * 4 + r;
        if (mA < N_NODES) {
          float x = acc0[nt][r] + bsum;
          x = (x > 0.f ? x : 0.f) * norm[mA];
          h1_fp8[((size_t)mA * 3 + stk) * 128 + colj] = f32_to_fp8(x);
        }
        if (mB < N_NODES) {
          float x = acc1[nt][r] + bsum;
          x = (x > 0.f ? x : 0.f) * norm[mB];
          h1_fp8[((size_t)mB * 3 + stk) * 128 + colj] = f32_to_fp8(x);
        }
      }
    }
  }
}

// layer-2 fused: out = (1/3) * sum_stk relu(agg[stk] @ w[stk] + feats @ v[stk] + bw + bv)
__global__ __launch_bounds__(256) void gemm_out_fused(
    const unsigned short* __restrict__ agg,
    const unsigned short* __restrict__ feats_bf,
    const unsigned short* __restrict__ Bt,
    const float* __restrict__ bwp, const float* __restrict__ bvp,
    float* __restrict__ outp) {
  __shared__ unsigned short Bs[64][256];
  int nh = blockIdx.y * 64;

  int tid = threadIdx.x;
  int lane = tid & 63;
  int wv = tid >> 6;
  int ln15 = lane & 15;
  int g = lane >> 4;

  int m0 = blockIdx.x * 128 + wv * 32;
  int r0 = m0 + ln15;
  int r1 = m0 + 16 + ln15;
  if (r0 >= N_NODES) r0 = N_NODES - 1;
  if (r1 >= N_NODES) r1 = N_NODES - 1;

  bf16x8 f0[4], f1[4];  // feats frags (k=128..255 phase), shared across stacks
#pragma unroll
  for (int s = 0; s < 4; ++s) {
    f0[s] = *(const bf16x8*)(feats_bf + (size_t)r0 * 128 + g * 8 + s * 32);
    f1[s] = *(const bf16x8*)(feats_bf + (size_t)r1 * 128 + g * 8 + s * 32);
  }

  f32x4 sum0[4], sum1[4];
#pragma unroll
  for (int nt = 0; nt < 4; ++nt) { sum0[nt] = (f32x4)(0.f); sum1[nt] = (f32x4)(0.f); }

  for (int stk = 0; stk < 3; ++stk) {
    if (stk) __syncthreads();
    stage_B64(Bs, Bt + (size_t)stk * 32768, nh, tid);
    __syncthreads();

    const unsigned short* A1 = agg + (size_t)stk * PLANE;
    bf16x8 g0[4], g1[4];
#pragma unroll
    for (int s = 0; s < 4; ++s) {
      g0[s] = *(const bf16x8*)(A1 + (size_t)r0 * 128 + g * 8 + s * 32);
      g1[s] = *(const bf16x8*)(A1 + (size_t)r1 * 128 + g * 8 + s * 32);
    }

    f32x4 acc0[4], acc1[4];
#pragma unroll
    for (int nt = 0; nt < 4; ++nt) { acc0[nt] = (f32x4)(0.f); acc1[nt] = (f32x4)(0.f); }

#pragma unroll
    for (int s = 0; s < 8; ++s) {
      bf16x8 af0 = (s < 4) ? g0[s & 3] : f0[s & 3];
      bf16x8 af1 = (s < 4) ? g1[s & 3] : f1[s & 3];
#pragma unroll
      for (int nt = 0; nt < 4; ++nt) {
        bf16x8 bfr = read_B64(Bs, nt * 16 + ln15, s * 4 + g);
        acc0[nt] = __builtin_amdgcn_mfma_f32_16x16x32_bf16(af0, bfr, acc0[nt], 0, 0, 0);
        acc1[nt] = __builtin_amdgcn_mfma_f32_16x16x32_bf16(af1, bfr, acc1[nt], 0, 0, 0);
      }
    }

#pragma unroll
    for (int nt = 0; nt < 4; ++nt) {
      int colj = nh + nt * 16 + ln15;
      float bsum = bwp[stk * 128 + colj] + bvp[stk * 128 + colj];
#pragma unroll
      for (int r = 0; r < 4; ++r) {
        float x0 = acc0[nt][r] + bsum;
        float x1 = acc1[nt][r] + bsum;
        sum0[nt][r] += (x0 > 0.f ? x0 : 0.f);
        sum1[nt][r] += (x1 > 0.f ? x1 : 0.f);
      }
    }
  }

  const float sc = 1.0f / 3.0f;
#pragma unroll
  for (int nt = 0; nt < 4; ++nt) {
    int colj = nh + nt * 16 + ln15;
#pragma unroll
    for (int r = 0; r < 4; ++r) {
      int mA = m0 + g * 4 + r;
      int mB = m0 + 16 + g * 4 + r;
      if (mA < N_NODES) outp[(size_t)mA * 128 + colj] = sum0[nt][r] * sc;
      if (mB < N_NODES) outp[(size_t)mB * 128 + colj] = sum1[nt][r] * sc;
    }
  }
}

// ---------------- launcher ----------------

extern "C" void kernel_launch(void* const* d_in, const int* in_sizes, int n_in,
                              void* d_out, int out_size, void* d_ws, size_t ws_size,
                              hipStream_t stream) {
  const float* feats = (const float*)d_in[0];
  const int* src = (const int*)d_in[1];
  const int* dst = (const int*)d_in[2];
  const float* w0 = (const float*)d_in[3];
  const float* b0 = (const float*)d_in[4];
  const float* w = (const float*)d_in[5];
  const float* bw = (const float*)d_in[6];
  const float* v = (const float*)d_in[7];
  const float* bv = (const float*)d_in[8];
  float* out = (float*)d_out;

  char* ws = (char*)d_ws;
  size_t off = 0;
  auto alloc = [&](size_t bytes) {
    void* p = ws + off;
    off += (bytes + 255) & ~(size_t)255;
    return p;
  };
  int* cnt = (int*)alloc(N_NODES * 4);
  int* local = (int*)alloc(N_NODES * 4);
  int* partial = (int*)alloc(NCHUNK * 4);
  int* chunk_off = (int*)alloc(NCHUNK * 4);
  float* norm = (float*)alloc(N_NODES * 4);
  int* rowptr = (int*)alloc((N_NODES + 1) * 4);
  int* cursor = (int*)alloc(N_NODES * 4);
  int* col = (int*)alloc(N_EDGES * 4);
  unsigned short* bt_h1 = (unsigned short*)alloc(3 * 32768 * 2);
  unsigned short* bt_out = (unsigned short*)alloc(3 * 32768 * 2);

  size_t pb = PLANE * 2;  // bf16 plane bytes
  unsigned short* feats_bf = (unsigned short*)alloc(pb);
  unsigned char* feats_fp8 = (unsigned char*)alloc(PLANE);
  unsigned short* P_bf = (unsigned short*)alloc(pb);
  unsigned char* h1_fp8 = (unsigned char*)alloc(3 * PLANE);  // [node][stk][128]
  unsigned short* agg_bf = (unsigned short*)alloc(3 * pb);   // [stk][node][128]

  hipMemsetAsync(cnt, 0, N_NODES * 4, stream);

  dim3 blk(256);
  count_deg<<<(N_EDGES + 255) / 256, blk, 0, stream>>>(dst, cnt);
  scan_local<<<NCHUNK, blk, 0, stream>>>(cnt, local, partial);
  scan_chunks<<<1, blk, 0, stream>>>(partial, chunk_off, rowptr);
  finalize_rows<<<NCHUNK, blk, 0, stream>>>(cnt, local, chunk_off, rowptr, cursor, norm);
  fill_csr<<<(N_EDGES + 255) / 256, blk, 0, stream>>>(src, dst, cursor, col);
  // prep needs norm (feats_fp8 is prescaled) -> after finalize_rows
  prep_all<<<(PREP_TOTAL + 255) / 256, blk, 0, stream>>>(feats, w0, w, v, norm, feats_bf,
                                                         feats_fp8, bt_h1, bt_out);

  int sblocks = 2048;  // persistent: 8192 waves, ~6 rows each
  int mblocks = (N_NODES + 127) / 128;
  dim3 ggrid(mblocks, 2);  // x: M-tile, y: N-half (stacks looped in-kernel)

  // P = propagate(feats)  (prescaled fp8 gather -> bf16 out)
  spmm_fp8<1><<<sblocks, blk, 0, stream>>>(feats_fp8, norm, rowptr, col, P_bf);
  // h1[k] = relu(P @ w0[k] + feats @ v[k] + b)  -> fp8, node-interleaved, *norm
  gemm_h1_fused<<<ggrid, blk, 0, stream>>>(P_bf, feats_bf, bt_h1, b0, bv, norm, h1_fp8);
  // agg[k] = propagate(h1[k])  (one 384 B region per edge)
  spmm_fp8<3><<<sblocks, blk, 0, stream>>>(h1_fp8, norm, rowptr, col, agg_bf);
  // out = (1/3) * sum_k relu(agg[k] @ w[k] + feats @ v[k] + bw[k] + bv[k])
  gemm_out_fused<<<ggrid, blk, 0, stream>>>(agg_bf, feats_bf, bt_out, bw, bv, out);
}

// Round 9
// 358.149 us; speedup vs baseline: 1.0618x; 1.0618x over previous
//
#include <hip/hip_runtime.h>

#define N_NODES 50000
#define N_EDGES 800000
#define D 128
#define PLANE ((size_t)N_NODES * D)
#define NCHUNK ((N_NODES + 255) / 256)  // 196

typedef float f32x4 __attribute__((ext_vector_type(4)));
typedef short bf16x8 __attribute__((ext_vector_type(8)));

__device__ __forceinline__ unsigned short f2bf(float x) {
  unsigned int u = __float_as_uint(x);
  u += 0x7FFFu + ((u >> 16) & 1u);  // RNE
  return (unsigned short)(u >> 16);
}
__device__ __forceinline__ float bf2f(unsigned short h) {
  return __uint_as_float((unsigned int)h << 16);
}

// ---------------- CSR build ----------------

__global__ __launch_bounds__(256) void scan_local(const int* __restrict__ cnt,
                                                  int* __restrict__ local,
                                                  int* __restrict__ partial) {
  __shared__ int s[256];
  int t = threadIdx.x;
  int i = blockIdx.x * 256 + t;
  int v = (i < N_NODES) ? cnt[i] : 0;
  s[t] = v;
  __syncthreads();
  for (int off = 1; off < 256; off <<= 1) {
    int tmp = (t >= off) ? s[t - off] : 0;
    __syncthreads();
    s[t] += tmp;
    __syncthreads();
  }
  if (i < N_NODES) local[i] = s[t] - v;
  if (t == 255) partial[blockIdx.x] = s[255];
}

__global__ __launch_bounds__(256) void scan_chunks(const int* __restrict__ partial,
                                                   int* __restrict__ chunk_off,
                                                   int* __restrict__ rowptr) {
  __shared__ int s[256];
  int t = threadIdx.x;
  int v = (t < NCHUNK) ? partial[t] : 0;
  s[t] = v;
  __syncthreads();
  for (int off = 1; off < 256; off <<= 1) {
    int tmp = (t >= off) ? s[t - off] : 0;
    __syncthreads();
    s[t] += tmp;
    __syncthreads();
  }
  if (t < NCHUNK) chunk_off[t] = s[t] - v;
  if (t == 255) rowptr[N_NODES] = s[255];
}

__global__ __launch_bounds__(256) void finalize_rows(const int* __restrict__ cnt,
                                                     const int* __restrict__ local,
                                                     const int* __restrict__ chunk_off,
                                                     int* __restrict__ rowptr,
                                                     int* __restrict__ cursor,
                                                     float* __restrict__ norm) {
  int i = blockIdx.x * 256 + threadIdx.x;
  if (i < N_NODES) {
    int r = local[i] + chunk_off[blockIdx.x];
    rowptr[i] = r;
    cursor[i] = r;
    int d = cnt[i];
    if (d < 1) d = 1;
    norm[i] = rsqrtf((float)d);
  }
}

__global__ __launch_bounds__(256) void fill_csr(const int* __restrict__ src,
                                                const int* __restrict__ dst,
                                                int* __restrict__ cursor,
                                                int* __restrict__ col) {
  int e = blockIdx.x * blockDim.x + threadIdx.x;
  if (e < N_EDGES) {
    int pos = atomicAdd(&cursor[dst[e]], 1);
    col[pos] = src[e];
  }
}

// ---------------- fused prep: feats->bf16 + weight transposes + degree count ----------------

#define CONV_THREADS ((int)(PLANE / 4))            // 1,600,000
#define WT_THREADS (2 * 3 * 128 * 256)             // 196,608
#define PREP_TOTAL (CONV_THREADS + WT_THREADS + N_EDGES)

__global__ __launch_bounds__(256) void prep_all(const float* __restrict__ feats,
                                                const float* __restrict__ w0,
                                                const float* __restrict__ w,
                                                const float* __restrict__ v,
                                                const int* __restrict__ dst,
                                                unsigned short* __restrict__ feats_bf,
                                                unsigned short* __restrict__ bt_h1,
                                                unsigned short* __restrict__ bt_out,
                                                int* __restrict__ cnt) {
  int idx = blockIdx.x * 256 + threadIdx.x;
  if (idx < CONV_THREADS) {
    float4 x = ((const float4*)feats)[idx];
    ushort4 o;
    o.x = f2bf(x.x);
    o.y = f2bf(x.y);
    o.z = f2bf(x.z);
    o.w = f2bf(x.w);
    ((ushort4*)feats_bf)[idx] = o;
    return;
  }
  idx -= CONV_THREADS;
  if (idx < WT_THREADS) {
    int buf = idx / 98304;
    int rem = idx - buf * 98304;
    int stack = rem / 32768;
    int rem2 = rem & 32767;
    int n = rem2 >> 8;
    int k = rem2 & 255;
    const float* srcm;
    int kk;
    if (k < 128) {
      srcm = (buf == 0) ? w0 : w;
      kk = k;
    } else {
      srcm = v;
      kk = k - 128;
    }
    float val = srcm[(size_t)stack * 16384 + (size_t)kk * 128 + n];
    unsigned short* dstb = (buf == 0) ? bt_h1 : bt_out;
    dstb[(size_t)stack * 32768 + (size_t)n * 256 + k] = f2bf(val);
    return;
  }
  idx -= WT_THREADS;
  if (idx < N_EDGES) atomicAdd(&cnt[dst[idx]], 1);
}

// ---------------- pull-mode SpMM, 4 edges/iter x unroll 4, 16 B/lane (R6-proven) ----------------

template <int NK>
__global__ __launch_bounds__(256) void spmm_bf(const unsigned short* __restrict__ h,
                                               const float* __restrict__ norm,
                                               const int* __restrict__ rowptr,
                                               const int* __restrict__ col,
                                               unsigned short* __restrict__ out) {
  int row = blockIdx.x * 4 + (threadIdx.x >> 6);
  if (row >= N_NODES) return;
  int lane = threadIdx.x & 63;
  int sub = lane >> 4;
  int c16 = lane & 15;
  int beg = rowptr[row], end = rowptr[row + 1];

  float acc[NK][8];
#pragma unroll
  for (int m = 0; m < NK; ++m)
#pragma unroll
    for (int j = 0; j < 8; ++j) acc[m][j] = 0.f;

#pragma unroll 4
  for (int e = beg; e < end; e += 4) {
    int eidx = e + sub;
    bool valid = eidx < end;
    int s = valid ? col[eidx] : 0;
    float wgt = valid ? norm[s] : 0.f;
    const unsigned short* hp = h + (size_t)s * D + c16 * 8;
#pragma unroll
    for (int m = 0; m < NK; ++m) {
      bf16x8 hv = *(const bf16x8*)(hp + m * PLANE);
#pragma unroll
      for (int j = 0; j < 8; ++j)
        acc[m][j] = fmaf(wgt, bf2f((unsigned short)hv[j]), acc[m][j]);
    }
  }

#pragma unroll
  for (int m = 0; m < NK; ++m)
#pragma unroll
    for (int j = 0; j < 8; ++j) {
      float vv = acc[m][j];
      vv += __shfl_xor(vv, 16);
      vv += __shfl_xor(vv, 32);
      acc[m][j] = vv;
    }

  if (sub == 0) {
    float nd = norm[row];
#pragma unroll
    for (int m = 0; m < NK; ++m) {
      bf16x8 ov;
#pragma unroll
      for (int j = 0; j < 8; ++j) ov[j] = (short)f2bf(acc[m][j] * nd);
      *(bf16x8*)(out + m * PLANE + (size_t)row * D + c16 * 8) = ov;
    }
  }
}

// ---------------- MFMA GEMM, full-N ----------------
// Block: 256 threads = 4 waves, M-tile 64 rows (wave = one 16-row strip),
// N-tile 128 (full). Full B^T per stack (128n x 256k bf16 = 64 KB) in LDS,
// XOR-swizzled: chunk c of row n at c ^ (n & 31) -> fragment reads 2-way max.
// Stacks looped in-kernel; A-fragments (shared across stacks) hoisted ONCE.
// Fragments (m89/m120-verified): A[m=lane&15][k=(lane>>4)*8+j];
// B-frag = Bt[n=lane&15][k..]; C/D col=lane&15, row=(lane>>4)*4+reg.

__device__ __forceinline__ void stage_B128(unsigned short (*Bs)[256],
                                           const unsigned short* __restrict__ Btg,
                                           int tid) {
#pragma unroll
  for (int i = 0; i < 16; ++i) {
    int t = tid + i * 256;       // 0..4095 16B-chunks
    int n = t >> 5;              // 0..127
    int kc = t & 31;
    int kcs = kc ^ (n & 31);     // swizzle
    *(bf16x8*)&Bs[n][kcs * 8] = *(const bf16x8*)(Btg + (size_t)n * 256 + kc * 8);
  }
}

__device__ __forceinline__ bf16x8 read_B128(const unsigned short (*Bs)[256], int n,
                                            int chunk) {
  return *(const bf16x8*)&Bs[n][(chunk ^ (n & 31)) * 8];
}

// layer-1: h1[stk] = relu(P @ w0[stk] + feats @ v[stk] + b0 + bv), bf16 planes
__global__ __launch_bounds__(256) void gemm_h1_fused(
    const unsigned short* __restrict__ P,
    const unsigned short* __restrict__ feats_bf,
    const unsigned short* __restrict__ Bt,
    const float* __restrict__ b0, const float* __restrict__ bv,
    unsigned short* __restrict__ h1_bf) {
  __shared__ unsigned short Bs[128][256];

  int tid = threadIdx.x;
  int lane = tid & 63;
  int wv = tid >> 6;
  int ln15 = lane & 15;
  int g = lane >> 4;

  int m0 = blockIdx.x * 64 + wv * 16;
  int r0 = m0 + ln15;
  if (r0 >= N_NODES) r0 = N_NODES - 1;

  bf16x8 a0[8];  // s=0..3 from P (k<128), s=4..7 from feats (k>=128)
#pragma unroll
  for (int s = 0; s < 4; ++s) {
    a0[s] = *(const bf16x8*)(P + (size_t)r0 * 128 + g * 8 + s * 32);
    a0[s + 4] = *(const bf16x8*)(feats_bf + (size_t)r0 * 128 + g * 8 + s * 32);
  }

  for (int stk = 0; stk < 3; ++stk) {
    if (stk) __syncthreads();
    stage_B128(Bs, Bt + (size_t)stk * 32768, tid);
    __syncthreads();

    f32x4 acc[8];
#pragma unroll
    for (int nt = 0; nt < 8; ++nt) acc[nt] = (f32x4)(0.f);

#pragma unroll
    for (int s = 0; s < 8; ++s) {
#pragma unroll
      for (int nt = 0; nt < 8; ++nt) {
        bf16x8 bfr = read_B128(Bs, nt * 16 + ln15, s * 4 + g);
        acc[nt] = __builtin_amdgcn_mfma_f32_16x16x32_bf16(a0[s], bfr, acc[nt], 0, 0, 0);
      }
    }

    unsigned short* outp = h1_bf + (size_t)stk * PLANE;
#pragma unroll
    for (int nt = 0; nt < 8; ++nt) {
      int colj = nt * 16 + ln15;
      float bsum = b0[stk * 128 + colj] + bv[stk * 128 + colj];
#pragma unroll
      for (int r = 0; r < 4; ++r) {
        int mA = m0 + g * 4 + r;
        if (mA < N_NODES) {
          float x = acc[nt][r] + bsum;
          outp[(size_t)mA * 128 + colj] = f2bf(x > 0.f ? x : 0.f);
        }
      }
    }
  }
}

// layer-2: out = (1/3) * sum_stk relu(agg[stk] @ w[stk] + feats @ v[stk] + bw + bv), fp32
__global__ __launch_bounds__(256) void gemm_out_fused(
    const unsigned short* __restrict__ agg,
    const unsigned short* __restrict__ feats_bf,
    const unsigned short* __restrict__ Bt,
    const float* __restrict__ bwp, const float* __restrict__ bvp,
    float* __restrict__ outp) {
  __shared__ unsigned short Bs[128][256];

  int tid = threadIdx.x;
  int lane = tid & 63;
  int wv = tid >> 6;
  int ln15 = lane & 15;
  int g = lane >> 4;

  int m0 = blockIdx.x * 64 + wv * 16;
  int r0 = m0 + ln15;
  if (r0 >= N_NODES) r0 = N_NODES - 1;

  bf16x8 f0[4];  // feats frags (k>=128 phase), shared across stacks
#pragma unroll
  for (int s = 0; s < 4; ++s)
    f0[s] = *(const bf16x8*)(feats_bf + (size_t)r0 * 128 + g * 8 + s * 32);

  f32x4 sum[8];
#pragma unroll
  for (int nt = 0; nt < 8; ++nt) sum[nt] = (f32x4)(0.f);

  for (int stk = 0; stk < 3; ++stk) {
    if (stk) __syncthreads();
    stage_B128(Bs, Bt + (size_t)stk * 32768, tid);
    __syncthreads();

    const unsigned short* A1 = agg + (size_t)stk * PLANE;
    bf16x8 g0[4];
#pragma unroll
    for (int s = 0; s < 4; ++s)
      g0[s] = *(const bf16x8*)(A1 + (size_t)r0 * 128 + g * 8 + s * 32);

    f32x4 acc[8];
#pragma unroll
    for (int nt = 0; nt < 8; ++nt) acc[nt] = (f32x4)(0.f);

#pragma unroll
    for (int s = 0; s < 8; ++s) {
      bf16x8 af = (s < 4) ? g0[s & 3] : f0[s & 3];
#pragma unroll
      for (int nt = 0; nt < 8; ++nt) {
        bf16x8 bfr = read_B128(Bs, nt * 16 + ln15, s * 4 + g);
        acc[nt] = __builtin_amdgcn_mfma_f32_16x16x32_bf16(af, bfr, acc[nt], 0, 0, 0);
      }
    }

#pragma unroll
    for (int nt = 0; nt < 8; ++nt) {
      int colj = nt * 16 + ln15;
      float bsum = bwp[stk * 128 + colj] + bvp[stk * 128 + colj];
#pragma unroll
      for (int r = 0; r < 4; ++r) {
        float x = acc[nt][r] + bsum;
        sum[nt][r] += (x > 0.f ? x : 0.f);
      }
    }
  }

  const float sc = 1.0f / 3.0f;
#pragma unroll
  for (int nt = 0; nt < 8; ++nt) {
    int colj = nt * 16 + ln15;
#pragma unroll
    for (int r = 0; r < 4; ++r) {
      int mA = m0 + g * 4 + r;
      if (mA < N_NODES) outp[(size_t)mA * 128 + colj] = sum[nt][r] * sc;
    }
  }
}

// ---------------- launcher ----------------

extern "C" void kernel_launch(void* const* d_in, const int* in_sizes, int n_in,
                              void* d_out, int out_size, void* d_ws, size_t ws_size,
                              hipStream_t stream) {
  const float* feats = (const float*)d_in[0];
  const int* src = (const int*)d_in[1];
  const int* dst = (const int*)d_in[2];
  const float* w0 = (const float*)d_in[3];
  const float* b0 = (const float*)d_in[4];
  const float* w = (const float*)d_in[5];
  const float* bw = (const float*)d_in[6];
  const float* v = (const float*)d_in[7];
  const float* bv = (const float*)d_in[8];
  float* out = (float*)d_out;

  char* ws = (char*)d_ws;
  size_t off = 0;
  auto alloc = [&](size_t bytes) {
    void* p = ws + off;
    off += (bytes + 255) & ~(size_t)255;
    return p;
  };
  int* cnt = (int*)alloc(N_NODES * 4);
  int* local = (int*)alloc(N_NODES * 4);
  int* partial = (int*)alloc(NCHUNK * 4);
  int* chunk_off = (int*)alloc(NCHUNK * 4);
  float* norm = (float*)alloc(N_NODES * 4);
  int* rowptr = (int*)alloc((N_NODES + 1) * 4);
  int* cursor = (int*)alloc(N_NODES * 4);
  int* col = (int*)alloc(N_EDGES * 4);
  unsigned short* bt_h1 = (unsigned short*)alloc(3 * 32768 * 2);
  unsigned short* bt_out = (unsigned short*)alloc(3 * 32768 * 2);

  size_t pb = PLANE * 2;  // bf16 plane bytes
  unsigned short* feats_bf = (unsigned short*)alloc(pb);
  unsigned short* P_bf = (unsigned short*)alloc(pb);
  unsigned short* h1_bf = (unsigned short*)alloc(3 * pb);   // [stk][node][128]
  unsigned short* agg_bf = (unsigned short*)alloc(3 * pb);  // [stk][node][128]

  hipMemsetAsync(cnt, 0, N_NODES * 4, stream);

  dim3 blk(256);
  // prep: feats->bf16, weight transposes, degree count (fused)
  prep_all<<<(PREP_TOTAL + 255) / 256, blk, 0, stream>>>(feats, w0, w, v, dst, feats_bf,
                                                         bt_h1, bt_out, cnt);
  scan_local<<<NCHUNK, blk, 0, stream>>>(cnt, local, partial);
  scan_chunks<<<1, blk, 0, stream>>>(partial, chunk_off, rowptr);
  finalize_rows<<<NCHUNK, blk, 0, stream>>>(cnt, local, chunk_off, rowptr, cursor, norm);
  fill_csr<<<(N_EDGES + 255) / 256, blk, 0, stream>>>(src, dst, cursor, col);

  int sblocks = (N_NODES + 3) / 4;
  int mblocks64 = (N_NODES + 63) / 64;  // 782, full-N GEMM grid

  // P = propagate(feats)   (shared across stacks)
  spmm_bf<1><<<sblocks, blk, 0, stream>>>(feats_bf, norm, rowptr, col, P_bf);
  // h1[k] = relu(P @ w0[k] + feats @ v[k] + b0[k] + bv[k])
  gemm_h1_fused<<<mblocks64, blk, 0, stream>>>(P_bf, feats_bf, bt_h1, b0, bv, h1_bf);
  // agg[k] = propagate(h1[k])
  spmm_bf<3><<<sblocks, blk, 0, stream>>>(h1_bf, norm, rowptr, col, agg_bf);
  // out = (1/3) * sum_k relu(agg[k] @ w[k] + feats @ v[k] + bw[k] + bv[k])
  gemm_out_fused<<<mblocks64, blk, 0, stream>>>(agg_bf, feats_bf, bt_out, bw, bv, out);
}